// Round 13
// baseline (150.444 us; speedup 1.0000x reference)
//
#include <hip/hip_runtime.h>
#include <math.h>

// ---------------- problem constants ----------------
#define NUM_CLASSES 80
#define TOPK 300
#define NTOT 10647             // 3*(169+676+2704)
#define L0END 507
#define L1END 2535
#define SELCAP 2048

// level 0: 13x13 (mask 6,7,8), level 1: 26x26 (mask 3,4,5), level 2: 52x52 (mask 0,1,2)
__constant__ float ANCWf[3][3] = {{116.f,156.f,373.f},{30.f,62.f,59.f},{10.f,16.f,33.f}};
__constant__ float ANCHf[3][3] = {{90.f,198.f,326.f},{61.f,45.f,119.f},{13.f,30.f,23.f}};

// correctly-rounded f32 exp (f64 exp, rounded once) — matches numpy f32 exp
__device__ __forceinline__ float expcr(float x) { return (float)exp((double)x); }
// numpy-style f32 sigmoid: op-by-op 1/(1+exp(-x)), each op f32 correctly rounded
__device__ __forceinline__ float sigf(float x) {
    float e = expcr(-x);
    return __fdiv_rn(1.0f, __fadd_rn(1.0f, e));
}

// locate anchor idx -> level geometry + channel-0 pointer (stride hw between channels)
__device__ __forceinline__ const float* locate(const float* f0, const float* f1, const float* f2,
                                               int img, int idx,
                                               int& level, int& hw, int& W, int& hrow, int& wcol, int& a) {
    int local, cell;
    const float* base;
    if (idx < L0END) {
        level = 0; local = idx; hw = 169; W = 13;
        base = f0 + (size_t)img * 43095;        // 255*169
    } else if (idx < L1END) {
        level = 1; local = idx - L0END; hw = 676; W = 26;
        base = f1 + (size_t)img * 172380;       // 255*676
    } else {
        level = 2; local = idx - L1END; hw = 2704; W = 52;
        base = f2 + (size_t)img * 689520;       // 255*2704
    }
    a = local / hw; cell = local - a * hw;
    hrow = cell / W; wcol = cell - hrow * W;
    return base + (size_t)(a * 85) * hw + cell;
}

// ---------------- kernel 1: numpy-f32 score -> dense key slots (no atomics) ----------------
__global__ void score_kernel(const float* __restrict__ f0, const float* __restrict__ f1,
                             const float* __restrict__ f2,
                             unsigned long long* __restrict__ keys) {
    int t = blockIdx.x * blockDim.x + threadIdx.x;

    if (t < 32 * 512) {
        // ---- level 0, scalar ----
        int img = t >> 9;
        int r = t & 511;
        if (r < 507) {
            int a = r / 169, cell = r - a * 169;
            const float* p = f0 + (size_t)img * 43095 + (size_t)(a * 85) * 169 + cell;
            float obj = sigf(p[4 * 169]);
            float mx = p[5 * 169];
            #pragma unroll 16
            for (int c = 1; c < NUM_CLASSES; ++c) {
                float v = p[(5 + c) * 169];
                if (v > mx) mx = v;
            }
            float s = __fmul_rn(obj, sigf(mx));
            unsigned long long kv = 0ULL;
            if (s >= 0.5f)
                kv = ((unsigned long long)__float_as_uint(s) << 32) | (unsigned int)(~(unsigned int)r);
            keys[(size_t)img * NTOT + r] = kv;
        }
    } else if (t < 64 * 512) {
        // ---- level 1, float4 (hw=676, strides %4==0 -> 16B aligned) ----
        int tt = t - 32 * 512;
        int img = tt >> 9;
        int r = tt & 511;
        if (r < 507) {
            int a = r / 169, grp = r - a * 169;
            int cell0 = grp * 4;
            const float* p0 = f1 + (size_t)img * 172380 + (size_t)(a * 85) * 676 + cell0;
            float4 o4 = *(const float4*)(p0 + 4 * 676);
            float4 mx = *(const float4*)(p0 + 5 * 676);
            #pragma unroll 16
            for (int c = 1; c < NUM_CLASSES; ++c) {
                float4 v = *(const float4*)(p0 + (5 + c) * 676);
                mx.x = fmaxf(mx.x, v.x); mx.y = fmaxf(mx.y, v.y);
                mx.z = fmaxf(mx.z, v.z); mx.w = fmaxf(mx.w, v.w);
            }
            float ob[4] = {o4.x, o4.y, o4.z, o4.w};
            float mv[4] = {mx.x, mx.y, mx.z, mx.w};
            unsigned long long* kout = keys + (size_t)img * NTOT + (L0END + a * 676 + cell0);
            #pragma unroll
            for (int j = 0; j < 4; ++j) {
                float s = __fmul_rn(sigf(ob[j]), sigf(mv[j]));
                unsigned int idx = L0END + a * 676 + cell0 + j;
                unsigned long long kv = 0ULL;
                if (s >= 0.5f)
                    kv = ((unsigned long long)__float_as_uint(s) << 32) | (unsigned int)(~idx);
                kout[j] = kv;
            }
        }
    } else {
        // ---- level 2, float4 (hw=2704) ----
        int tt = t - 64 * 512;
        int img = tt >> 11;
        int r = tt & 2047;
        if (r < 2028) {
            int a = r / 676, grp = r - a * 676;
            int cell0 = grp * 4;
            const float* p0 = f2 + (size_t)img * 689520 + (size_t)(a * 85) * 2704 + cell0;
            float4 o4 = *(const float4*)(p0 + 4 * 2704);
            float4 mx = *(const float4*)(p0 + 5 * 2704);
            #pragma unroll 16
            for (int c = 1; c < NUM_CLASSES; ++c) {
                float4 v = *(const float4*)(p0 + (5 + c) * 2704);
                mx.x = fmaxf(mx.x, v.x); mx.y = fmaxf(mx.y, v.y);
                mx.z = fmaxf(mx.z, v.z); mx.w = fmaxf(mx.w, v.w);
            }
            float ob[4] = {o4.x, o4.y, o4.z, o4.w};
            float mv[4] = {mx.x, mx.y, mx.z, mx.w};
            unsigned long long* kout = keys + (size_t)img * NTOT + (L1END + a * 2704 + cell0);
            #pragma unroll
            for (int j = 0; j < 4; ++j) {
                float s = __fmul_rn(sigf(ob[j]), sigf(mv[j]));
                unsigned int idx = L1END + a * 2704 + cell0 + j;
                unsigned long long kv = 0ULL;
                if (s >= 0.5f)
                    kv = ((unsigned long long)__float_as_uint(s) << 32) | (unsigned int)(~idx);
                kout[j] = kv;
            }
        }
    }
}

// ---------------- kernel 2: fused top-300 + decode + NMS (one block per image) ----------------
// topk: histogram select + exact pairwise rank (keys unique; (score desc, idx asc)
// ties exactly like lax.top_k). decode: wave per selected row, literal per-class
// sigmoid argmax. NMS: ballot bit-matrix + lane-parallel greedy scan.
__global__ __launch_bounds__(1024) void topk_nms_kernel(const float* __restrict__ f0,
                                                        const float* __restrict__ f1,
                                                        const float* __restrict__ f2,
                                                        const unsigned long long* __restrict__ keys,
                                                        float* __restrict__ out) {
    __shared__ unsigned long long s[NTOT];      // 85,176 B — staged keys
    __shared__ unsigned int hist[1024];
    __shared__ unsigned long long sel[SELCAP];  // 16 KiB
    __shared__ unsigned int wsum[16], wsuf[16];
    __shared__ unsigned int cnt;
    __shared__ int Tbin;
    __shared__ unsigned int tidx[TOPK];
    __shared__ float bx0[TOPK], bx1[TOPK], bx2[TOPK], bx3[TOPK];
    __shared__ float bb0[TOPK], bb1[TOPK], bb2[TOPK], bb3[TOPK];
    __shared__ float area[TOPK], sc[TOPK], clsf[TOPK];
    __shared__ unsigned long long sup[TOPK][5];
    __shared__ unsigned long long keepm[5];

    int img = blockIdx.x;
    int tid = threadIdx.x;
    int wv = tid >> 6, ln = tid & 63;
    const unsigned long long* k = keys + (size_t)img * NTOT;

    hist[tid] = 0;
    if (tid == 0) { cnt = 0; Tbin = 0; }
    for (int i = tid; i < TOPK; i += 1024) tidx[i] = 0xFFFFFFFFu;
    __syncthreads();

    // ---- stage + histogram in one global pass ----
    for (int i = tid; i < NTOT; i += 1024) {
        unsigned long long kv = k[i];
        s[i] = kv;
        unsigned int sb = (unsigned int)(kv >> 32);
        int bin = (int)(sb - 0x3F000000u) >> 13;   // negative for zero keys
        if (bin >= 0) {
            if (bin > 1023) bin = 1023;
            atomicAdd(&hist[bin], 1u);
        }
    }
    __syncthreads();

    // ---- wave-level suffix scan of hist ----
    unsigned int ssum = hist[tid];
    #pragma unroll
    for (int off = 1; off < 64; off <<= 1) {
        unsigned int o = __shfl_down(ssum, off, 64);
        if (ln + off < 64) ssum += o;
    }
    if (ln == 0) wsum[wv] = ssum;
    __syncthreads();
    if (wv == 0) {
        unsigned int tws = (ln < 16) ? wsum[ln] : 0u;
        #pragma unroll
        for (int off = 1; off < 16; off <<= 1) {
            unsigned int o = __shfl_down(tws, off, 64);
            if (ln + off < 16) tws += o;
        }
        if (ln < 16) wsuf[ln] = tws;   // wsuf[w] = sum over waves >= w
    }
    __syncthreads();
    {
        unsigned int higher = (wv < 15) ? wsuf[wv + 1] : 0u;
        unsigned int scanval = ssum + higher;                  // suffix sum from this bin
        unsigned int down1 = __shfl_down(scanval, 1, 64);
        unsigned int nextval = (ln < 63) ? down1 : higher;     // scan of bin+1 (tid=1023 -> 0)
        if (scanval >= TOPK && nextval < TOPK) Tbin = tid;     // unique transition
    }
    __syncthreads();
    int T = Tbin;

    // ---- select from LDS: bin >= T ----
    for (int i = tid; i < NTOT; i += 1024) {
        unsigned long long kv = s[i];
        unsigned int sb = (unsigned int)(kv >> 32);
        int bin = (int)(sb - 0x3F000000u) >> 13;
        if (bin > 1023) bin = 1023;
        if (bin >= T) {
            unsigned int pos = atomicAdd(&cnt, 1u);
            if (pos < SELCAP) sel[pos] = kv;
        }
    }
    __syncthreads();
    int m = (int)cnt; if (m > SELCAP) m = SELCAP;

    // ---- exact rank by pairwise comparison, scatter idx by rank into LDS ----
    for (int i = tid; i < m; i += 1024) {
        unsigned long long ki = sel[i];
        int rank = 0;
        for (int j = 0; j < m; ++j) rank += (sel[j] > ki);
        if (rank < TOPK) tidx[rank] = ~((unsigned int)ki);
    }
    __syncthreads();

    // ---- decode: one wave per selected row ----
    for (int kk = wv; kk < TOPK; kk += 16) {
        unsigned int idx = tidx[kk];
        if (idx == 0xFFFFFFFFu) {
            if (ln == 0) {
                bx0[kk] = 0.f; bx1[kk] = 0.f; bx2[kk] = 0.f; bx3[kk] = 0.f;
                bb0[kk] = 0.f; bb1[kk] = 0.f; bb2[kk] = 0.f; bb3[kk] = 0.f;
                area[kk] = 0.f; sc[kk] = 0.f; clsf[kk] = 0.f;
            }
        } else {
            int level, hw, W, hrow, wcol, a;
            const float* p = locate(f0, f1, f2, img, (int)idx, level, hw, W, hrow, wcol, a);

            // literal per-class sigmoid argmax, wave-parallel, first-max-wins
            float v1 = p[(5 + ln) * hw];
            float bestv = sigf(v1);
            int besti = ln;
            if (ln < 16) {
                float v2 = p[(69 + ln) * hw];
                float sv2 = sigf(v2);
                if (sv2 > bestv) { bestv = sv2; besti = 64 + ln; }   // tie keeps smaller index
            }
            #pragma unroll
            for (int off = 32; off > 0; off >>= 1) {
                float ov = __shfl_xor(bestv, off, 64);
                int oi = __shfl_xor(besti, off, 64);
                if (ov > bestv || (ov == bestv && oi < besti)) { bestv = ov; besti = oi; }
            }

            float tval = (ln < 5) ? p[ln * hw] : 0.0f;
            float tx = __shfl(tval, 0, 64);
            float ty = __shfl(tval, 1, 64);
            float tw = __shfl(tval, 2, 64);
            float th = __shfl(tval, 3, 64);
            float tob = __shfl(tval, 4, 64);

            if (ln == 0) {
                float x = __fdiv_rn(__fadd_rn(sigf(tx), (float)wcol), (float)W);
                float y = __fdiv_rn(__fadd_rn(sigf(ty), (float)hrow), (float)W);   // H == W per level
                float wd = __fdiv_rn(__fmul_rn(expcr(tw), ANCWf[level][a]), 416.0f);
                float ht = __fdiv_rn(__fmul_rn(expcr(th), ANCHf[level][a]), 416.0f);
                float obj = sigf(tob);
                float score = __fmul_rn(obj, bestv);
                if (!(score >= 0.5f)) score = 0.0f;

                float hx = __fmul_rn(wd, 0.5f);
                float hy = __fmul_rn(ht, 0.5f);
                float x1 = __fmul_rn(__fsub_rn(x, hx), 416.0f);
                float y1 = __fmul_rn(__fsub_rn(y, hy), 416.0f);
                float x2 = __fmul_rn(__fadd_rn(x, hx), 416.0f);
                float y2 = __fmul_rn(__fadd_rn(y, hy), 416.0f);
                float cf = (float)besti;
                float off2 = __fmul_rn(cf, 832.0f);   // 2*INPUT

                bx0[kk] = x1; bx1[kk] = y1; bx2[kk] = x2; bx3[kk] = y2;
                float b0 = __fadd_rn(x1, off2), b1 = __fadd_rn(y1, off2);
                float b2 = __fadd_rn(x2, off2), b3 = __fadd_rn(y2, off2);
                bb0[kk] = b0; bb1[kk] = b1; bb2[kk] = b2; bb3[kk] = b3;
                area[kk] = __fmul_rn(__fsub_rn(b2, b0), __fsub_rn(b3, b1));
                sc[kk] = score;
                clsf[kk] = cf;
            }
        }
    }
    __syncthreads();

    // ---- suppression bit-matrix, wave-parallel; lane's j-box in registers per w ----
    #pragma unroll
    for (int w = 0; w < 5; ++w) {
        int j = (w << 6) + ln;
        bool jv = (j < TOPK);
        float j0 = jv ? bb0[j] : 0.0f;
        float j1 = jv ? bb1[j] : 0.0f;
        float j2 = jv ? bb2[j] : 0.0f;
        float j3 = jv ? bb3[j] : 0.0f;
        float ja = jv ? area[j] : 0.0f;
        for (int r = wv; r < TOPK; r += 16) {
            float a0 = bb0[r], a1 = bb1[r], a2 = bb2[r], a3 = bb3[r], aa = area[r];
            bool bit = false;
            if (jv && j > r) {
                float ltx = fmaxf(a0, j0);
                float lty = fmaxf(a1, j1);
                float rbx = fminf(a2, j2);
                float rby = fminf(a3, j3);
                float wx = fmaxf(__fsub_rn(rbx, ltx), 0.0f);
                float wy = fmaxf(__fsub_rn(rby, lty), 0.0f);
                float inter = __fmul_rn(wx, wy);
                float denom = __fadd_rn(__fsub_rn(__fadd_rn(aa, ja), inter), 1e-6f);
                float iou = __fdiv_rn(inter, denom);
                bit = (iou > 0.3f);
            }
            unsigned long long mm = __ballot(bit);
            if (ln == 0) sup[r][w] = mm;
        }
    }
    __syncthreads();

    // ---- lane-parallel greedy scan by wave 0: lane w (w<5) owns keep-word kp ----
    if (wv == 0) {
        unsigned long long kp = ~0ULL;
        for (int i = 0; i < TOPK; ++i) {
            unsigned long long kw = __shfl(kp, i >> 6, 64);
            bool keep_i = (kw >> (i & 63)) & 1ULL;
            if (keep_i && ln < 5) kp &= ~sup[i][ln];
        }
        if (ln < 5) keepm[ln] = kp;
    }
    __syncthreads();

    if (tid < TOPK) {
        bool kept = (keepm[tid >> 6] >> (tid & 63)) & 1ULL;
        float mmask = (kept && (sc[tid] > 0.0f)) ? 1.0f : 0.0f;
        float* o = out + ((size_t)img * TOPK + tid) * 6;
        o[0] = __fmul_rn(bx0[tid], mmask);
        o[1] = __fmul_rn(bx1[tid], mmask);
        o[2] = __fmul_rn(bx2[tid], mmask);
        o[3] = __fmul_rn(bx3[tid], mmask);
        o[4] = __fmul_rn(sc[tid], mmask);
        o[5] = __fmul_rn(clsf[tid], mmask);
    }
}

extern "C" void kernel_launch(void* const* d_in, const int* in_sizes, int n_in,
                              void* d_out, int out_size, void* d_ws, size_t ws_size,
                              hipStream_t stream) {
    const float* f0 = (const float*)d_in[0];
    const float* f1 = (const float*)d_in[1];
    const float* f2 = (const float*)d_in[2];
    float* out = (float*)d_out;

    int B = in_sizes[0] / 43095;   // 255*13*13 (== 32 for this problem)

    // workspace: [keys B*NTOT u64]
    unsigned long long* keys = (unsigned long long*)d_ws;

    // threads: 32*512 (L0) + 32*512 (L1) + 32*2048 (L2) = 98304
    score_kernel<<<98304 / 256, 256, 0, stream>>>(f0, f1, f2, keys);
    topk_nms_kernel<<<B, 1024, 0, stream>>>(f0, f1, f2, keys, out);
}

// Round 14
// 149.020 us; speedup vs baseline: 1.0096x; 1.0096x over previous
//
#include <hip/hip_runtime.h>
#include <math.h>

// ---------------- problem constants ----------------
#define NUM_CLASSES 80
#define TOPK 300
#define NTOT 10647             // 3*(169+676+2704)
#define L0END 507
#define L1END 2535
#define SELCAP 2048
#define CSTR 10656             // per-image cls stride: L0 [0,512) L1 [512,2540) L2 [2540,10652)
#define DELTA 0.25f            // near-max candidate window for exact sigmoid-argmax

// level 0: 13x13 (mask 6,7,8), level 1: 26x26 (mask 3,4,5), level 2: 52x52 (mask 0,1,2)
__constant__ float ANCWf[3][3] = {{116.f,156.f,373.f},{30.f,62.f,59.f},{10.f,16.f,33.f}};
__constant__ float ANCHf[3][3] = {{90.f,198.f,326.f},{61.f,45.f,119.f},{13.f,30.f,23.f}};

// correctly-rounded f32 exp (f64 exp, rounded once) — matches numpy f32 exp
__device__ __forceinline__ float expcr(float x) { return (float)exp((double)x); }
// numpy-style f32 sigmoid: op-by-op 1/(1+exp(-x)), each op f32 correctly rounded
__device__ __forceinline__ float sigf(float x) {
    float e = expcr(-x);
    return __fdiv_rn(1.0f, __fadd_rn(1.0f, e));
}

// locate anchor idx -> level geometry + channel-0 pointer (stride hw between channels)
__device__ __forceinline__ const float* locate(const float* f0, const float* f1, const float* f2,
                                               int img, int idx,
                                               int& level, int& hw, int& W, int& hrow, int& wcol, int& a) {
    int local, cell;
    const float* base;
    if (idx < L0END) {
        level = 0; local = idx; hw = 169; W = 13;
        base = f0 + (size_t)img * 43095;        // 255*169
    } else if (idx < L1END) {
        level = 1; local = idx - L0END; hw = 676; W = 26;
        base = f1 + (size_t)img * 172380;       // 255*676
    } else {
        level = 2; local = idx - L1END; hw = 2704; W = 52;
        base = f2 + (size_t)img * 689520;       // 255*2704
    }
    a = local / hw; cell = local - a * hw;
    hrow = cell / W; wcol = cell - hrow * W;
    return base + (size_t)(a * 85) * hw + cell;
}

// ---------------- kernel 1: numpy-f32 score -> dense keys + class byte ----------------
// keys[img*NTOT+idx] = score>=0.5 ? (score_bits<<32 | ~idx) : 0 (every slot written).
// cls8: exact first-wins argmax over per-class CR-f32 sigmoids, written only for
// thresholded anchors. Exactness: ref argmax = first c with sigf(l_c)==sigf(vmax);
// monotone CR sigmoid => such c has l_c >= vmax - w, w <= ulp/slope ~ 3e-5 << DELTA.
__global__ void score_kernel(const float* __restrict__ f0, const float* __restrict__ f1,
                             const float* __restrict__ f2,
                             unsigned long long* __restrict__ keys,
                             unsigned char* __restrict__ cls8) {
    int t = blockIdx.x * blockDim.x + threadIdx.x;

    if (t < 32 * 512) {
        // ---- level 0, scalar ----
        int img = t >> 9;
        int r = t & 511;
        if (r < 507) {
            int a = r / 169, cell = r - a * 169;
            const float* p = f0 + (size_t)img * 43095 + (size_t)(a * 85) * 169 + cell;
            float obj = sigf(p[4 * 169]);
            float mx = p[5 * 169];
            #pragma unroll 16
            for (int c = 1; c < NUM_CLASSES; ++c) {
                float v = p[(5 + c) * 169];
                if (v > mx) mx = v;
            }
            float smax = sigf(mx);
            float s = __fmul_rn(obj, smax);
            unsigned long long kv = 0ULL;
            if (s >= 0.5f)
                kv = ((unsigned long long)__float_as_uint(s) << 32) | (unsigned int)(~(unsigned int)r);
            keys[(size_t)img * NTOT + r] = kv;
            if (s >= 0.5f) {
                int cls = 0;
                for (int c = 0; c < NUM_CLASSES; ++c) {
                    float v = p[(5 + c) * 169];
                    if (v >= mx - DELTA && sigf(v) == smax) { cls = c; break; }
                }
                cls8[(size_t)img * CSTR + r] = (unsigned char)cls;
            }
        }
    } else if (t < 64 * 512) {
        // ---- level 1, float4 (hw=676, strides %4==0 -> 16B aligned) ----
        int tt = t - 32 * 512;
        int img = tt >> 9;
        int r = tt & 511;
        if (r < 507) {
            int a = r / 169, grp = r - a * 169;
            int cell0 = grp * 4;
            const float* p0 = f1 + (size_t)img * 172380 + (size_t)(a * 85) * 676 + cell0;
            float4 o4 = *(const float4*)(p0 + 4 * 676);
            float4 mx4 = *(const float4*)(p0 + 5 * 676);
            #pragma unroll 16
            for (int c = 1; c < NUM_CLASSES; ++c) {
                float4 v = *(const float4*)(p0 + (5 + c) * 676);
                mx4.x = fmaxf(mx4.x, v.x); mx4.y = fmaxf(mx4.y, v.y);
                mx4.z = fmaxf(mx4.z, v.z); mx4.w = fmaxf(mx4.w, v.w);
            }
            float ob[4] = {o4.x, o4.y, o4.z, o4.w};
            float mv[4] = {mx4.x, mx4.y, mx4.z, mx4.w};
            float smaxv[4]; bool need[4];
            unsigned long long* kout = keys + (size_t)img * NTOT + (L0END + a * 676 + cell0);
            #pragma unroll
            for (int j = 0; j < 4; ++j) {
                smaxv[j] = sigf(mv[j]);
                float s = __fmul_rn(sigf(ob[j]), smaxv[j]);
                unsigned int idx = L0END + a * 676 + cell0 + j;
                unsigned long long kv = 0ULL;
                if (s >= 0.5f)
                    kv = ((unsigned long long)__float_as_uint(s) << 32) | (unsigned int)(~idx);
                kout[j] = kv;
                need[j] = (s >= 0.5f);
            }
            if (need[0] || need[1] || need[2] || need[3]) {
                int clsv[4] = {0, 0, 0, 0};
                bool done[4] = {!need[0], !need[1], !need[2], !need[3]};
                for (int c = 0; c < NUM_CLASSES; ++c) {
                    float4 v = *(const float4*)(p0 + (5 + c) * 676);
                    float vv[4] = {v.x, v.y, v.z, v.w};
                    #pragma unroll
                    for (int j = 0; j < 4; ++j) {
                        if (!done[j] && vv[j] >= mv[j] - DELTA && sigf(vv[j]) == smaxv[j]) {
                            clsv[j] = c; done[j] = true;
                        }
                    }
                    if (done[0] && done[1] && done[2] && done[3]) break;
                }
                size_t cb = (size_t)img * CSTR + 512 + a * 676 + cell0;
                #pragma unroll
                for (int j = 0; j < 4; ++j)
                    if (need[j]) cls8[cb + j] = (unsigned char)clsv[j];
            }
        }
    } else {
        // ---- level 2, float4 (hw=2704) ----
        int tt = t - 64 * 512;
        int img = tt >> 11;
        int r = tt & 2047;
        if (r < 2028) {
            int a = r / 676, grp = r - a * 676;
            int cell0 = grp * 4;
            const float* p0 = f2 + (size_t)img * 689520 + (size_t)(a * 85) * 2704 + cell0;
            float4 o4 = *(const float4*)(p0 + 4 * 2704);
            float4 mx4 = *(const float4*)(p0 + 5 * 2704);
            #pragma unroll 16
            for (int c = 1; c < NUM_CLASSES; ++c) {
                float4 v = *(const float4*)(p0 + (5 + c) * 2704);
                mx4.x = fmaxf(mx4.x, v.x); mx4.y = fmaxf(mx4.y, v.y);
                mx4.z = fmaxf(mx4.z, v.z); mx4.w = fmaxf(mx4.w, v.w);
            }
            float ob[4] = {o4.x, o4.y, o4.z, o4.w};
            float mv[4] = {mx4.x, mx4.y, mx4.z, mx4.w};
            float smaxv[4]; bool need[4];
            unsigned long long* kout = keys + (size_t)img * NTOT + (L1END + a * 2704 + cell0);
            #pragma unroll
            for (int j = 0; j < 4; ++j) {
                smaxv[j] = sigf(mv[j]);
                float s = __fmul_rn(sigf(ob[j]), smaxv[j]);
                unsigned int idx = L1END + a * 2704 + cell0 + j;
                unsigned long long kv = 0ULL;
                if (s >= 0.5f)
                    kv = ((unsigned long long)__float_as_uint(s) << 32) | (unsigned int)(~idx);
                kout[j] = kv;
                need[j] = (s >= 0.5f);
            }
            if (need[0] || need[1] || need[2] || need[3]) {
                int clsv[4] = {0, 0, 0, 0};
                bool done[4] = {!need[0], !need[1], !need[2], !need[3]};
                for (int c = 0; c < NUM_CLASSES; ++c) {
                    float4 v = *(const float4*)(p0 + (5 + c) * 2704);
                    float vv[4] = {v.x, v.y, v.z, v.w};
                    #pragma unroll
                    for (int j = 0; j < 4; ++j) {
                        if (!done[j] && vv[j] >= mv[j] - DELTA && sigf(vv[j]) == smaxv[j]) {
                            clsv[j] = c; done[j] = true;
                        }
                    }
                    if (done[0] && done[1] && done[2] && done[3]) break;
                }
                size_t cb = (size_t)img * CSTR + 2540 + a * 2704 + cell0;
                #pragma unroll
                for (int j = 0; j < 4; ++j)
                    if (need[j]) cls8[cb + j] = (unsigned char)clsv[j];
            }
        }
    }
}

// ---------------- kernel 2: top-300 — LDS-staged histogram select + exact rank ----------------
__global__ __launch_bounds__(1024) void topk_kernel(const unsigned long long* __restrict__ keys,
                                                    unsigned int* __restrict__ top_idx) {
    __shared__ unsigned long long s[NTOT];      // 85,176 B — staged keys
    __shared__ unsigned int hist[1024];
    __shared__ unsigned long long sel[SELCAP];  // 16 KiB
    __shared__ unsigned int wsum[16], wsuf[16];
    __shared__ unsigned int cnt;
    __shared__ int Tbin;

    int img = blockIdx.x;
    int tid = threadIdx.x;
    int wv = tid >> 6, ln = tid & 63;
    const unsigned long long* k = keys + (size_t)img * NTOT;

    hist[tid] = 0;
    if (tid == 0) { cnt = 0; Tbin = 0; }
    for (int i = tid; i < TOPK; i += 1024) top_idx[img * TOPK + i] = 0xFFFFFFFFu;
    __syncthreads();

    // stage + histogram in one global pass
    for (int i = tid; i < NTOT; i += 1024) {
        unsigned long long kv = k[i];
        s[i] = kv;
        unsigned int sb = (unsigned int)(kv >> 32);
        int bin = (int)(sb - 0x3F000000u) >> 13;   // negative for zero keys
        if (bin >= 0) {
            if (bin > 1023) bin = 1023;
            atomicAdd(&hist[bin], 1u);
        }
    }
    __syncthreads();

    // wave-level suffix scan of hist (scan[b] = sum_{b'>=b} hist[b'])
    unsigned int ssum = hist[tid];
    #pragma unroll
    for (int off = 1; off < 64; off <<= 1) {
        unsigned int o = __shfl_down(ssum, off, 64);
        if (ln + off < 64) ssum += o;
    }
    if (ln == 0) wsum[wv] = ssum;
    __syncthreads();
    if (wv == 0) {
        unsigned int tws = (ln < 16) ? wsum[ln] : 0u;
        #pragma unroll
        for (int off = 1; off < 16; off <<= 1) {
            unsigned int o = __shfl_down(tws, off, 64);
            if (ln + off < 16) tws += o;
        }
        if (ln < 16) wsuf[ln] = tws;   // wsuf[w] = sum over waves >= w
    }
    __syncthreads();
    {
        unsigned int higher = (wv < 15) ? wsuf[wv + 1] : 0u;
        unsigned int scanval = ssum + higher;                  // suffix sum from this bin
        unsigned int down1 = __shfl_down(scanval, 1, 64);
        unsigned int nextval = (ln < 63) ? down1 : higher;     // scan of bin+1 (tid=1023 -> 0)
        if (scanval >= TOPK && nextval < TOPK) Tbin = tid;     // unique transition
    }
    __syncthreads();
    int T = Tbin;

    // select from LDS: bin >= T
    for (int i = tid; i < NTOT; i += 1024) {
        unsigned long long kv = s[i];
        unsigned int sb = (unsigned int)(kv >> 32);
        int bin = (int)(sb - 0x3F000000u) >> 13;
        if (bin > 1023) bin = 1023;
        if (bin >= T) {
            unsigned int pos = atomicAdd(&cnt, 1u);
            if (pos < SELCAP) sel[pos] = kv;
        }
    }
    __syncthreads();
    int m = (int)cnt; if (m > SELCAP) m = SELCAP;

    // exact rank by pairwise comparison (keys unique), scatter rank < 300
    for (int i = tid; i < m; i += 1024) {
        unsigned long long ki = sel[i];
        int rank = 0;
        for (int j = 0; j < m; ++j) rank += (sel[j] > ki);
        if (rank < TOPK) top_idx[img * TOPK + rank] = ~((unsigned int)ki);
    }
}

// ---------------- kernel 3: slim decode + NMS (ballot bit-matrix + lane scan) ----------------
__global__ __launch_bounds__(1024) void nms_kernel(const float* __restrict__ f0,
                                                   const float* __restrict__ f1,
                                                   const float* __restrict__ f2,
                                                   const unsigned long long* __restrict__ keys,
                                                   const unsigned char* __restrict__ cls8,
                                                   const unsigned int* __restrict__ top_idx,
                                                   float* __restrict__ out) {
    __shared__ float bx0[TOPK], bx1[TOPK], bx2[TOPK], bx3[TOPK];
    __shared__ float bb0[TOPK], bb1[TOPK], bb2[TOPK], bb3[TOPK];
    __shared__ float area[TOPK], sc[TOPK], clsf[TOPK];
    __shared__ unsigned long long sup[TOPK][5];
    __shared__ unsigned long long keepm[5];

    int img = blockIdx.x;
    int tid = threadIdx.x;
    int wv = tid >> 6, ln = tid & 63;

    if (tid < TOPK) {
        unsigned int idx = top_idx[img * TOPK + tid];
        if (idx == 0xFFFFFFFFu) {
            bx0[tid] = 0.f; bx1[tid] = 0.f; bx2[tid] = 0.f; bx3[tid] = 0.f;
            bb0[tid] = 0.f; bb1[tid] = 0.f; bb2[tid] = 0.f; bb3[tid] = 0.f;
            area[tid] = 0.f; sc[tid] = 0.f; clsf[tid] = 0.f;
        } else {
            int level, hw, W, hrow, wcol, a;
            const float* p = locate(f0, f1, f2, img, (int)idx, level, hw, W, hrow, wcol, a);
            float tx = p[0];
            float ty = p[hw];
            float tw = p[2 * hw];
            float th = p[3 * hw];
            float score = __uint_as_float((unsigned int)(keys[(size_t)img * NTOT + idx] >> 32));
            int co = (idx < L0END) ? (int)idx
                     : (idx < L1END ? 512 + (int)idx - L0END : 2540 + (int)idx - L1END);
            int cid = cls8[(size_t)img * CSTR + co];

            float x = __fdiv_rn(__fadd_rn(sigf(tx), (float)wcol), (float)W);
            float y = __fdiv_rn(__fadd_rn(sigf(ty), (float)hrow), (float)W);   // H == W per level
            float wd = __fdiv_rn(__fmul_rn(expcr(tw), ANCWf[level][a]), 416.0f);
            float ht = __fdiv_rn(__fmul_rn(expcr(th), ANCHf[level][a]), 416.0f);

            float hx = __fmul_rn(wd, 0.5f);
            float hy = __fmul_rn(ht, 0.5f);
            float x1 = __fmul_rn(__fsub_rn(x, hx), 416.0f);
            float y1 = __fmul_rn(__fsub_rn(y, hy), 416.0f);
            float x2 = __fmul_rn(__fadd_rn(x, hx), 416.0f);
            float y2 = __fmul_rn(__fadd_rn(y, hy), 416.0f);
            float cf = (float)cid;
            float off = __fmul_rn(cf, 832.0f);   // 2*INPUT

            bx0[tid] = x1; bx1[tid] = y1; bx2[tid] = x2; bx3[tid] = y2;
            float b0 = __fadd_rn(x1, off), b1 = __fadd_rn(y1, off);
            float b2 = __fadd_rn(x2, off), b3 = __fadd_rn(y2, off);
            bb0[tid] = b0; bb1[tid] = b1; bb2[tid] = b2; bb3[tid] = b3;
            area[tid] = __fmul_rn(__fsub_rn(b2, b0), __fsub_rn(b3, b1));
            sc[tid] = score;
            clsf[tid] = cf;
        }
    }
    __syncthreads();

    // suppression bit-matrix, wave-parallel; lane's j-box kept in registers per w.
    #pragma unroll
    for (int w = 0; w < 5; ++w) {
        int j = (w << 6) + ln;
        bool jv = (j < TOPK);
        float j0 = jv ? bb0[j] : 0.0f;
        float j1 = jv ? bb1[j] : 0.0f;
        float j2 = jv ? bb2[j] : 0.0f;
        float j3 = jv ? bb3[j] : 0.0f;
        float ja = jv ? area[j] : 0.0f;
        for (int r = wv; r < TOPK; r += 16) {
            float a0 = bb0[r], a1 = bb1[r], a2 = bb2[r], a3 = bb3[r], aa = area[r];
            bool bit = false;
            if (jv && j > r) {
                float ltx = fmaxf(a0, j0);
                float lty = fmaxf(a1, j1);
                float rbx = fminf(a2, j2);
                float rby = fminf(a3, j3);
                float wx = fmaxf(__fsub_rn(rbx, ltx), 0.0f);
                float wy = fmaxf(__fsub_rn(rby, lty), 0.0f);
                float inter = __fmul_rn(wx, wy);
                float denom = __fadd_rn(__fsub_rn(__fadd_rn(aa, ja), inter), 1e-6f);
                float iou = __fdiv_rn(inter, denom);
                bit = (iou > 0.3f);
            }
            unsigned long long mm = __ballot(bit);
            if (ln == 0) sup[r][w] = mm;
        }
    }
    __syncthreads();

    // lane-parallel greedy scan by wave 0: lane w (w<5) owns keep-word kp.
    if (wv == 0) {
        unsigned long long kp = ~0ULL;
        for (int i = 0; i < TOPK; ++i) {
            unsigned long long kw = __shfl(kp, i >> 6, 64);
            bool keep_i = (kw >> (i & 63)) & 1ULL;
            if (keep_i && ln < 5) kp &= ~sup[i][ln];
        }
        if (ln < 5) keepm[ln] = kp;
    }
    __syncthreads();

    if (tid < TOPK) {
        bool kept = (keepm[tid >> 6] >> (tid & 63)) & 1ULL;
        float m = (kept && (sc[tid] > 0.0f)) ? 1.0f : 0.0f;
        float* o = out + ((size_t)img * TOPK + tid) * 6;
        o[0] = __fmul_rn(bx0[tid], m);
        o[1] = __fmul_rn(bx1[tid], m);
        o[2] = __fmul_rn(bx2[tid], m);
        o[3] = __fmul_rn(bx3[tid], m);
        o[4] = __fmul_rn(sc[tid], m);
        o[5] = __fmul_rn(clsf[tid], m);
    }
}

extern "C" void kernel_launch(void* const* d_in, const int* in_sizes, int n_in,
                              void* d_out, int out_size, void* d_ws, size_t ws_size,
                              hipStream_t stream) {
    const float* f0 = (const float*)d_in[0];
    const float* f1 = (const float*)d_in[1];
    const float* f2 = (const float*)d_in[2];
    float* out = (float*)d_out;

    int B = in_sizes[0] / 43095;   // 255*13*13 (== 32 for this problem)

    // workspace: [keys B*NTOT u64][cls8 B*CSTR u8][top_idx B*300 u32]
    unsigned long long* keys = (unsigned long long*)d_ws;
    size_t off1 = (size_t)B * NTOT * sizeof(unsigned long long);
    unsigned char* cls8 = (unsigned char*)d_ws + off1;
    size_t off2 = (off1 + (size_t)B * CSTR + 255) / 256 * 256;
    unsigned int* top_idx = (unsigned int*)((char*)d_ws + off2);

    // threads: 32*512 (L0) + 32*512 (L1) + 32*2048 (L2) = 98304
    score_kernel<<<98304 / 256, 256, 0, stream>>>(f0, f1, f2, keys, cls8);
    topk_kernel<<<B, 1024, 0, stream>>>(keys, top_idx);
    nms_kernel<<<B, 1024, 0, stream>>>(f0, f1, f2, keys, cls8, top_idx, out);
}

// Round 15
// 129.347 us; speedup vs baseline: 1.1631x; 1.1521x over previous
//
#include <hip/hip_runtime.h>
#include <math.h>

// ---------------- problem constants ----------------
#define NUM_CLASSES 80
#define TOPK 300
#define NTOT 10647             // 3*(169+676+2704)
#define L0END 507
#define L1END 2535
#define SELCAP 2048
#define CSTR 10656             // per-image cls stride: L0 [0,512) L1 [512,2540) L2 [2540,10652)
#define DELTA 0.25f            // near-max candidate window for exact sigmoid-argmax
#define NEARW 1e-3f            // m1-m2 gap below which sigf collision is possible

// level 0: 13x13 (mask 6,7,8), level 1: 26x26 (mask 3,4,5), level 2: 52x52 (mask 0,1,2)
__constant__ float ANCWf[3][3] = {{116.f,156.f,373.f},{30.f,62.f,59.f},{10.f,16.f,33.f}};
__constant__ float ANCHf[3][3] = {{90.f,198.f,326.f},{61.f,45.f,119.f},{13.f,30.f,23.f}};

// correctly-rounded f32 exp (f64 exp, rounded once) — matches numpy f32 exp
__device__ __forceinline__ float expcr(float x) { return (float)exp((double)x); }
// numpy-style f32 sigmoid: op-by-op 1/(1+exp(-x)), each op f32 correctly rounded
__device__ __forceinline__ float sigf(float x) {
    float e = expcr(-x);
    return __fdiv_rn(1.0f, __fadd_rn(1.0f, e));
}

// locate anchor idx -> level geometry + channel-0 pointer (stride hw between channels)
__device__ __forceinline__ const float* locate(const float* f0, const float* f1, const float* f2,
                                               int img, int idx,
                                               int& level, int& hw, int& W, int& hrow, int& wcol, int& a) {
    int local, cell;
    const float* base;
    if (idx < L0END) {
        level = 0; local = idx; hw = 169; W = 13;
        base = f0 + (size_t)img * 43095;        // 255*169
    } else if (idx < L1END) {
        level = 1; local = idx - L0END; hw = 676; W = 26;
        base = f1 + (size_t)img * 172380;       // 255*676
    } else {
        level = 2; local = idx - L1END; hw = 2704; W = 52;
        base = f2 + (size_t)img * 689520;       // 255*2704
    }
    a = local / hw; cell = local - a * hw;
    hrow = cell / W; wcol = cell - hrow * W;
    return base + (size_t)(a * 85) * hw + cell;
}

// exact first-wins sigmoid-argmax fallback (rare): first c with sigf(l_c)==smax
__device__ __forceinline__ int argmax_fallback(const float* p0, int hw, int joff,
                                               float m1, float smax) {
    for (int c = 0; c < NUM_CLASSES; ++c) {
        float v = p0[(5 + c) * hw + joff];
        if (v >= m1 - DELTA && sigf(v) == smax) return c;
    }
    return 0;
}

// ---------------- kernel 1: numpy-f32 score -> dense keys + class byte ----------------
// keys[img*NTOT+idx] = score>=0.5 ? (score_bits<<32 | ~idx) : 0 (every slot written).
// cls: tracked in-pass as (m1,m2,ci); logit-argmax == sigmoid-argmax whenever
// m2 < m1-NEARW and m1<=8 (sigf strictly increasing over that gap); else exact
// serial fallback. Semantics bit-identical to the literal per-class argmax.
__global__ void score_kernel(const float* __restrict__ f0, const float* __restrict__ f1,
                             const float* __restrict__ f2,
                             unsigned long long* __restrict__ keys,
                             unsigned char* __restrict__ cls8) {
    int t = blockIdx.x * blockDim.x + threadIdx.x;

    if (t < 32 * 512) {
        // ---- level 0, scalar ----
        int img = t >> 9;
        int r = t & 511;
        if (r < 507) {
            int a = r / 169, cell = r - a * 169;
            const float* p = f0 + (size_t)img * 43095 + (size_t)(a * 85) * 169 + cell;
            float obj = sigf(p[4 * 169]);
            float m1 = p[5 * 169], m2 = -1e30f;
            int ci = 0;
            #pragma unroll 16
            for (int c = 1; c < NUM_CLASSES; ++c) {
                float v = p[(5 + c) * 169];
                if (v > m1) { m2 = m1; m1 = v; ci = c; }
                else m2 = fmaxf(m2, v);
            }
            float smax = sigf(m1);
            float s = __fmul_rn(obj, smax);
            unsigned long long kv = 0ULL;
            if (s >= 0.5f)
                kv = ((unsigned long long)__float_as_uint(s) << 32) | (unsigned int)(~(unsigned int)r);
            keys[(size_t)img * NTOT + r] = kv;
            if (s >= 0.5f) {
                int cid = ci;
                if (m2 >= m1 - NEARW || m1 > 8.0f)
                    cid = argmax_fallback(p, 169, 0, m1, smax);
                cls8[(size_t)img * CSTR + r] = (unsigned char)cid;
            }
        }
    } else if (t < 64 * 512) {
        // ---- level 1, float4 (hw=676, strides %4==0 -> 16B aligned) ----
        int tt = t - 32 * 512;
        int img = tt >> 9;
        int r = tt & 511;
        if (r < 507) {
            int a = r / 169, grp = r - a * 169;
            int cell0 = grp * 4;
            const float* p0 = f1 + (size_t)img * 172380 + (size_t)(a * 85) * 676 + cell0;
            float4 o4 = *(const float4*)(p0 + 4 * 676);
            float4 f = *(const float4*)(p0 + 5 * 676);
            float m1v[4] = {f.x, f.y, f.z, f.w};
            float m2v[4] = {-1e30f, -1e30f, -1e30f, -1e30f};
            int civ[4] = {0, 0, 0, 0};
            #pragma unroll 16
            for (int c = 1; c < NUM_CLASSES; ++c) {
                float4 v4 = *(const float4*)(p0 + (5 + c) * 676);
                float vv[4] = {v4.x, v4.y, v4.z, v4.w};
                #pragma unroll
                for (int j = 0; j < 4; ++j) {
                    if (vv[j] > m1v[j]) { m2v[j] = m1v[j]; m1v[j] = vv[j]; civ[j] = c; }
                    else m2v[j] = fmaxf(m2v[j], vv[j]);
                }
            }
            float ob[4] = {o4.x, o4.y, o4.z, o4.w};
            unsigned long long* kout = keys + (size_t)img * NTOT + (L0END + a * 676 + cell0);
            size_t cb = (size_t)img * CSTR + 512 + a * 676 + cell0;
            #pragma unroll
            for (int j = 0; j < 4; ++j) {
                float smax = sigf(m1v[j]);
                float s = __fmul_rn(sigf(ob[j]), smax);
                unsigned int idx = L0END + a * 676 + cell0 + j;
                unsigned long long kv = 0ULL;
                if (s >= 0.5f)
                    kv = ((unsigned long long)__float_as_uint(s) << 32) | (unsigned int)(~idx);
                kout[j] = kv;
                if (s >= 0.5f) {
                    int cid = civ[j];
                    if (m2v[j] >= m1v[j] - NEARW || m1v[j] > 8.0f)
                        cid = argmax_fallback(p0, 676, j, m1v[j], smax);
                    cls8[cb + j] = (unsigned char)cid;
                }
            }
        }
    } else {
        // ---- level 2, float4 (hw=2704) ----
        int tt = t - 64 * 512;
        int img = tt >> 11;
        int r = tt & 2047;
        if (r < 2028) {
            int a = r / 676, grp = r - a * 676;
            int cell0 = grp * 4;
            const float* p0 = f2 + (size_t)img * 689520 + (size_t)(a * 85) * 2704 + cell0;
            float4 o4 = *(const float4*)(p0 + 4 * 2704);
            float4 f = *(const float4*)(p0 + 5 * 2704);
            float m1v[4] = {f.x, f.y, f.z, f.w};
            float m2v[4] = {-1e30f, -1e30f, -1e30f, -1e30f};
            int civ[4] = {0, 0, 0, 0};
            #pragma unroll 16
            for (int c = 1; c < NUM_CLASSES; ++c) {
                float4 v4 = *(const float4*)(p0 + (5 + c) * 2704);
                float vv[4] = {v4.x, v4.y, v4.z, v4.w};
                #pragma unroll
                for (int j = 0; j < 4; ++j) {
                    if (vv[j] > m1v[j]) { m2v[j] = m1v[j]; m1v[j] = vv[j]; civ[j] = c; }
                    else m2v[j] = fmaxf(m2v[j], vv[j]);
                }
            }
            float ob[4] = {o4.x, o4.y, o4.z, o4.w};
            unsigned long long* kout = keys + (size_t)img * NTOT + (L1END + a * 2704 + cell0);
            size_t cb = (size_t)img * CSTR + 2540 + a * 2704 + cell0;
            #pragma unroll
            for (int j = 0; j < 4; ++j) {
                float smax = sigf(m1v[j]);
                float s = __fmul_rn(sigf(ob[j]), smax);
                unsigned int idx = L1END + a * 2704 + cell0 + j;
                unsigned long long kv = 0ULL;
                if (s >= 0.5f)
                    kv = ((unsigned long long)__float_as_uint(s) << 32) | (unsigned int)(~idx);
                kout[j] = kv;
                if (s >= 0.5f) {
                    int cid = civ[j];
                    if (m2v[j] >= m1v[j] - NEARW || m1v[j] > 8.0f)
                        cid = argmax_fallback(p0, 2704, j, m1v[j], smax);
                    cls8[cb + j] = (unsigned char)cid;
                }
            }
        }
    }
}

// ---------------- kernel 2: top-300 — LDS-staged histogram select + exact rank ----------------
__global__ __launch_bounds__(1024) void topk_kernel(const unsigned long long* __restrict__ keys,
                                                    unsigned int* __restrict__ top_idx) {
    __shared__ unsigned long long s[NTOT];      // 85,176 B — staged keys
    __shared__ unsigned int hist[1024];
    __shared__ unsigned long long sel[SELCAP];  // 16 KiB
    __shared__ unsigned int wsum[16], wsuf[16];
    __shared__ unsigned int cnt;
    __shared__ int Tbin;

    int img = blockIdx.x;
    int tid = threadIdx.x;
    int wv = tid >> 6, ln = tid & 63;
    const unsigned long long* k = keys + (size_t)img * NTOT;

    hist[tid] = 0;
    if (tid == 0) { cnt = 0; Tbin = 0; }
    for (int i = tid; i < TOPK; i += 1024) top_idx[img * TOPK + i] = 0xFFFFFFFFu;
    __syncthreads();

    // stage + histogram in one global pass
    for (int i = tid; i < NTOT; i += 1024) {
        unsigned long long kv = k[i];
        s[i] = kv;
        unsigned int sb = (unsigned int)(kv >> 32);
        int bin = (int)(sb - 0x3F000000u) >> 13;   // negative for zero keys
        if (bin >= 0) {
            if (bin > 1023) bin = 1023;
            atomicAdd(&hist[bin], 1u);
        }
    }
    __syncthreads();

    // wave-level suffix scan of hist (scan[b] = sum_{b'>=b} hist[b'])
    unsigned int ssum = hist[tid];
    #pragma unroll
    for (int off = 1; off < 64; off <<= 1) {
        unsigned int o = __shfl_down(ssum, off, 64);
        if (ln + off < 64) ssum += o;
    }
    if (ln == 0) wsum[wv] = ssum;
    __syncthreads();
    if (wv == 0) {
        unsigned int tws = (ln < 16) ? wsum[ln] : 0u;
        #pragma unroll
        for (int off = 1; off < 16; off <<= 1) {
            unsigned int o = __shfl_down(tws, off, 64);
            if (ln + off < 16) tws += o;
        }
        if (ln < 16) wsuf[ln] = tws;   // wsuf[w] = sum over waves >= w
    }
    __syncthreads();
    {
        unsigned int higher = (wv < 15) ? wsuf[wv + 1] : 0u;
        unsigned int scanval = ssum + higher;                  // suffix sum from this bin
        unsigned int down1 = __shfl_down(scanval, 1, 64);
        unsigned int nextval = (ln < 63) ? down1 : higher;     // scan of bin+1 (tid=1023 -> 0)
        if (scanval >= TOPK && nextval < TOPK) Tbin = tid;     // unique transition
    }
    __syncthreads();
    int T = Tbin;

    // select from LDS: bin >= T
    for (int i = tid; i < NTOT; i += 1024) {
        unsigned long long kv = s[i];
        unsigned int sb = (unsigned int)(kv >> 32);
        int bin = (int)(sb - 0x3F000000u) >> 13;
        if (bin > 1023) bin = 1023;
        if (bin >= T) {
            unsigned int pos = atomicAdd(&cnt, 1u);
            if (pos < SELCAP) sel[pos] = kv;
        }
    }
    __syncthreads();
    int m = (int)cnt; if (m > SELCAP) m = SELCAP;

    // exact rank by pairwise comparison (keys unique), scatter rank < 300
    for (int i = tid; i < m; i += 1024) {
        unsigned long long ki = sel[i];
        int rank = 0;
        for (int j = 0; j < m; ++j) rank += (sel[j] > ki);
        if (rank < TOPK) top_idx[img * TOPK + rank] = ~((unsigned int)ki);
    }
}

// ---------------- kernel 3: slim decode + NMS (ballot bit-matrix + lane scan) ----------------
__global__ __launch_bounds__(1024) void nms_kernel(const float* __restrict__ f0,
                                                   const float* __restrict__ f1,
                                                   const float* __restrict__ f2,
                                                   const unsigned long long* __restrict__ keys,
                                                   const unsigned char* __restrict__ cls8,
                                                   const unsigned int* __restrict__ top_idx,
                                                   float* __restrict__ out) {
    __shared__ float bx0[TOPK], bx1[TOPK], bx2[TOPK], bx3[TOPK];
    __shared__ float bb0[TOPK], bb1[TOPK], bb2[TOPK], bb3[TOPK];
    __shared__ float area[TOPK], sc[TOPK], clsf[TOPK];
    __shared__ unsigned long long sup[TOPK][5];
    __shared__ unsigned long long keepm[5];

    int img = blockIdx.x;
    int tid = threadIdx.x;
    int wv = tid >> 6, ln = tid & 63;

    if (tid < TOPK) {
        unsigned int idx = top_idx[img * TOPK + tid];
        if (idx == 0xFFFFFFFFu) {
            bx0[tid] = 0.f; bx1[tid] = 0.f; bx2[tid] = 0.f; bx3[tid] = 0.f;
            bb0[tid] = 0.f; bb1[tid] = 0.f; bb2[tid] = 0.f; bb3[tid] = 0.f;
            area[tid] = 0.f; sc[tid] = 0.f; clsf[tid] = 0.f;
        } else {
            int level, hw, W, hrow, wcol, a;
            const float* p = locate(f0, f1, f2, img, (int)idx, level, hw, W, hrow, wcol, a);
            float tx = p[0];
            float ty = p[hw];
            float tw = p[2 * hw];
            float th = p[3 * hw];
            float score = __uint_as_float((unsigned int)(keys[(size_t)img * NTOT + idx] >> 32));
            int co = (idx < L0END) ? (int)idx
                     : (idx < L1END ? 512 + (int)idx - L0END : 2540 + (int)idx - L1END);
            int cid = cls8[(size_t)img * CSTR + co];

            float x = __fdiv_rn(__fadd_rn(sigf(tx), (float)wcol), (float)W);
            float y = __fdiv_rn(__fadd_rn(sigf(ty), (float)hrow), (float)W);   // H == W per level
            float wd = __fdiv_rn(__fmul_rn(expcr(tw), ANCWf[level][a]), 416.0f);
            float ht = __fdiv_rn(__fmul_rn(expcr(th), ANCHf[level][a]), 416.0f);

            float hx = __fmul_rn(wd, 0.5f);
            float hy = __fmul_rn(ht, 0.5f);
            float x1 = __fmul_rn(__fsub_rn(x, hx), 416.0f);
            float y1 = __fmul_rn(__fsub_rn(y, hy), 416.0f);
            float x2 = __fmul_rn(__fadd_rn(x, hx), 416.0f);
            float y2 = __fmul_rn(__fadd_rn(y, hy), 416.0f);
            float cf = (float)cid;
            float off = __fmul_rn(cf, 832.0f);   // 2*INPUT

            bx0[tid] = x1; bx1[tid] = y1; bx2[tid] = x2; bx3[tid] = y2;
            float b0 = __fadd_rn(x1, off), b1 = __fadd_rn(y1, off);
            float b2 = __fadd_rn(x2, off), b3 = __fadd_rn(y2, off);
            bb0[tid] = b0; bb1[tid] = b1; bb2[tid] = b2; bb3[tid] = b3;
            area[tid] = __fmul_rn(__fsub_rn(b2, b0), __fsub_rn(b3, b1));
            sc[tid] = score;
            clsf[tid] = cf;
        }
    }
    __syncthreads();

    // suppression bit-matrix, wave-parallel; lane's j-box kept in registers per w.
    #pragma unroll
    for (int w = 0; w < 5; ++w) {
        int j = (w << 6) + ln;
        bool jv = (j < TOPK);
        float j0 = jv ? bb0[j] : 0.0f;
        float j1 = jv ? bb1[j] : 0.0f;
        float j2 = jv ? bb2[j] : 0.0f;
        float j3 = jv ? bb3[j] : 0.0f;
        float ja = jv ? area[j] : 0.0f;
        for (int r = wv; r < TOPK; r += 16) {
            float a0 = bb0[r], a1 = bb1[r], a2 = bb2[r], a3 = bb3[r], aa = area[r];
            bool bit = false;
            if (jv && j > r) {
                float ltx = fmaxf(a0, j0);
                float lty = fmaxf(a1, j1);
                float rbx = fminf(a2, j2);
                float rby = fminf(a3, j3);
                float wx = fmaxf(__fsub_rn(rbx, ltx), 0.0f);
                float wy = fmaxf(__fsub_rn(rby, lty), 0.0f);
                float inter = __fmul_rn(wx, wy);
                float denom = __fadd_rn(__fsub_rn(__fadd_rn(aa, ja), inter), 1e-6f);
                float iou = __fdiv_rn(inter, denom);
                bit = (iou > 0.3f);
            }
            unsigned long long mm = __ballot(bit);
            if (ln == 0) sup[r][w] = mm;
        }
    }
    __syncthreads();

    // lane-parallel greedy scan by wave 0: lane w (w<5) owns keep-word kp.
    if (wv == 0) {
        unsigned long long kp = ~0ULL;
        for (int i = 0; i < TOPK; ++i) {
            unsigned long long kw = __shfl(kp, i >> 6, 64);
            bool keep_i = (kw >> (i & 63)) & 1ULL;
            if (keep_i && ln < 5) kp &= ~sup[i][ln];
        }
        if (ln < 5) keepm[ln] = kp;
    }
    __syncthreads();

    if (tid < TOPK) {
        bool kept = (keepm[tid >> 6] >> (tid & 63)) & 1ULL;
        float m = (kept && (sc[tid] > 0.0f)) ? 1.0f : 0.0f;
        float* o = out + ((size_t)img * TOPK + tid) * 6;
        o[0] = __fmul_rn(bx0[tid], m);
        o[1] = __fmul_rn(bx1[tid], m);
        o[2] = __fmul_rn(bx2[tid], m);
        o[3] = __fmul_rn(bx3[tid], m);
        o[4] = __fmul_rn(sc[tid], m);
        o[5] = __fmul_rn(clsf[tid], m);
    }
}

extern "C" void kernel_launch(void* const* d_in, const int* in_sizes, int n_in,
                              void* d_out, int out_size, void* d_ws, size_t ws_size,
                              hipStream_t stream) {
    const float* f0 = (const float*)d_in[0];
    const float* f1 = (const float*)d_in[1];
    const float* f2 = (const float*)d_in[2];
    float* out = (float*)d_out;

    int B = in_sizes[0] / 43095;   // 255*13*13 (== 32 for this problem)

    // workspace: [keys B*NTOT u64][cls8 B*CSTR u8][top_idx B*300 u32]
    unsigned long long* keys = (unsigned long long*)d_ws;
    size_t off1 = (size_t)B * NTOT * sizeof(unsigned long long);
    unsigned char* cls8 = (unsigned char*)d_ws + off1;
    size_t off2 = (off1 + (size_t)B * CSTR + 255) / 256 * 256;
    unsigned int* top_idx = (unsigned int*)((char*)d_ws + off2);

    // threads: 32*512 (L0) + 32*512 (L1) + 32*2048 (L2) = 98304
    score_kernel<<<98304 / 256, 256, 0, stream>>>(f0, f1, f2, keys, cls8);
    topk_kernel<<<B, 1024, 0, stream>>>(keys, top_idx);
    nms_kernel<<<B, 1024, 0, stream>>>(f0, f1, f2, keys, cls8, top_idx, out);
}

// Round 16
// 113.486 us; speedup vs baseline: 1.3257x; 1.1398x over previous
//
#include <hip/hip_runtime.h>
#include <math.h>

// ---------------- problem constants ----------------
#define NUM_CLASSES 80
#define TOPK 300
#define NTOT 10647             // 3*(169+676+2704)
#define L0END 507
#define L1END 2535
#define SELCAP 2048
#define CSTR 10656             // per-image cls stride: L0 [0,512) L1 [512,2540) L2 [2540,10652)
#define DELTA 0.25f            // near-max candidate window for exact sigmoid-argmax
#define NEARW 1e-3f            // m1-m2 gap below which sigf collision is possible

// level 0: 13x13 (mask 6,7,8), level 1: 26x26 (mask 3,4,5), level 2: 52x52 (mask 0,1,2)
__constant__ float ANCWf[3][3] = {{116.f,156.f,373.f},{30.f,62.f,59.f},{10.f,16.f,33.f}};
__constant__ float ANCHf[3][3] = {{90.f,198.f,326.f},{61.f,45.f,119.f},{13.f,30.f,23.f}};

// correctly-rounded f32 exp (f64 exp, rounded once) — matches numpy f32 exp
__device__ __forceinline__ float expcr(float x) { return (float)exp((double)x); }
// numpy-style f32 sigmoid: op-by-op 1/(1+exp(-x)), each op f32 correctly rounded
__device__ __forceinline__ float sigf(float x) {
    float e = expcr(-x);
    return __fdiv_rn(1.0f, __fadd_rn(1.0f, e));
}

// locate anchor idx -> level geometry + channel-0 pointer (stride hw between channels)
__device__ __forceinline__ const float* locate(const float* f0, const float* f1, const float* f2,
                                               int img, int idx,
                                               int& level, int& hw, int& W, int& hrow, int& wcol, int& a) {
    int local, cell;
    const float* base;
    if (idx < L0END) {
        level = 0; local = idx; hw = 169; W = 13;
        base = f0 + (size_t)img * 43095;        // 255*169
    } else if (idx < L1END) {
        level = 1; local = idx - L0END; hw = 676; W = 26;
        base = f1 + (size_t)img * 172380;       // 255*676
    } else {
        level = 2; local = idx - L1END; hw = 2704; W = 52;
        base = f2 + (size_t)img * 689520;       // 255*2704
    }
    a = local / hw; cell = local - a * hw;
    hrow = cell / W; wcol = cell - hrow * W;
    return base + (size_t)(a * 85) * hw + cell;
}

// exact first-wins sigmoid-argmax fallback (rare): first c with sigf(l_c)==smax
__device__ __forceinline__ int argmax_fallback(const float* p0, int hw, int joff,
                                               float m1, float smax) {
    for (int c = 0; c < NUM_CLASSES; ++c) {
        float v = p0[(5 + c) * hw + joff];
        if (v >= m1 - DELTA && sigf(v) == smax) return c;
    }
    return 0;
}

// cross-chunk combine of (m1,m2,ci): A = lower channel chunk wins ties (first-wins).
__device__ __forceinline__ void comb_step(float& m1, float& m2, int& ci, int xorOff, bool iAmLow) {
    float pm1 = __shfl_xor(m1, xorOff, 64);
    float pm2 = __shfl_xor(m2, xorOff, 64);
    int   pci = __shfl_xor(ci, xorOff, 64);
    float am1 = iAmLow ? m1 : pm1, am2 = iAmLow ? m2 : pm2;
    float bm1 = iAmLow ? pm1 : m1, bm2 = iAmLow ? pm2 : m2;
    int   aci = iAmLow ? ci : pci, bci = iAmLow ? pci : ci;
    if (bm1 > am1) { m1 = bm1; ci = bci; m2 = fmaxf(bm2, am1); }
    else           { m1 = am1; ci = aci; m2 = fmaxf(am2, bm1); }
}

// ---------------- kernel 1: numpy-f32 score -> dense keys + class byte ----------------
// 4-way channel-split: lanes {g, g+16, g+32, g+48} each scan 20 classes for one
// anchor group, combine (m1,m2,ci) via shfl_xor(16),(32) — bit-identical to the
// sequential first-wins strict-> scan. cls via logit-argmax unless m2>=m1-NEARW
// or m1>8 (sigf collision possible) -> exact serial fallback.
// Thread ranges (all wave-aligned per image):
//   L0 [0, 65536):        img=t>>11, u=t&2047, r=(u>>6)*16+(ln&15) <507, scalar
//   L1 [65536, 131072):   same mapping, groups of 4 cells (float4)
//   L2 [131072, 393216):  img=tt>>13, u=tt&8191, r=(u>>6)*16+(ln&15) <2028
__global__ void score_kernel(const float* __restrict__ f0, const float* __restrict__ f1,
                             const float* __restrict__ f2,
                             unsigned long long* __restrict__ keys,
                             unsigned char* __restrict__ cls8) {
    int t = blockIdx.x * blockDim.x + threadIdx.x;
    int lane = threadIdx.x & 63;
    int chunk = (lane >> 4);
    int cbase = 20 * chunk;
    bool low1 = ((chunk & 1) == 0);
    bool low2 = ((chunk & 2) == 0);

    if (t < 65536) {
        // ---- level 0, scalar, 4-lane channel split ----
        int img = t >> 11;
        int u = t & 2047;
        int r = ((u >> 6) << 4) + (lane & 15);
        if (r < 507) {
            int a = r / 169, cell = r - a * 169;
            const float* p = f0 + (size_t)img * 43095 + (size_t)(a * 85) * 169 + cell;
            float m1 = p[(5 + cbase) * 169], m2 = -1e30f;
            int ci = cbase;
            #pragma unroll
            for (int c = 1; c < 20; ++c) {
                float v = p[(5 + cbase + c) * 169];
                if (v > m1) { m2 = m1; m1 = v; ci = cbase + c; }
                else m2 = fmaxf(m2, v);
            }
            comb_step(m1, m2, ci, 16, low1);
            comb_step(m1, m2, ci, 32, low2);
            if (chunk == 0) {
                float smax = sigf(m1);
                float s = __fmul_rn(sigf(p[4 * 169]), smax);
                unsigned long long kv = 0ULL;
                if (s >= 0.5f)
                    kv = ((unsigned long long)__float_as_uint(s) << 32) | (unsigned int)(~(unsigned int)r);
                keys[(size_t)img * NTOT + r] = kv;
                if (s >= 0.5f) {
                    int cid = ci;
                    if (m2 >= m1 - NEARW || m1 > 8.0f)
                        cid = argmax_fallback(p, 169, 0, m1, smax);
                    cls8[(size_t)img * CSTR + r] = (unsigned char)cid;
                }
            }
        }
    } else if (t < 131072) {
        // ---- level 1, float4 groups, 4-lane channel split ----
        int tt = t - 65536;
        int img = tt >> 11;
        int u = tt & 2047;
        int r = ((u >> 6) << 4) + (lane & 15);
        if (r < 507) {
            int a = r / 169, grp = r - a * 169;
            int cell0 = grp * 4;
            const float* p0 = f1 + (size_t)img * 172380 + (size_t)(a * 85) * 676 + cell0;
            float4 v4 = *(const float4*)(p0 + (5 + cbase) * 676);
            float m1v[4] = {v4.x, v4.y, v4.z, v4.w};
            float m2v[4] = {-1e30f, -1e30f, -1e30f, -1e30f};
            int civ[4] = {cbase, cbase, cbase, cbase};
            #pragma unroll
            for (int c = 1; c < 20; ++c) {
                float4 w4 = *(const float4*)(p0 + (5 + cbase + c) * 676);
                float vv[4] = {w4.x, w4.y, w4.z, w4.w};
                #pragma unroll
                for (int j = 0; j < 4; ++j) {
                    if (vv[j] > m1v[j]) { m2v[j] = m1v[j]; m1v[j] = vv[j]; civ[j] = cbase + c; }
                    else m2v[j] = fmaxf(m2v[j], vv[j]);
                }
            }
            #pragma unroll
            for (int j = 0; j < 4; ++j) {
                comb_step(m1v[j], m2v[j], civ[j], 16, low1);
                comb_step(m1v[j], m2v[j], civ[j], 32, low2);
            }
            // lane chunk==j finalizes cell j
            float4 o4 = *(const float4*)(p0 + 4 * 676);
            float obv[4] = {o4.x, o4.y, o4.z, o4.w};
            int j = chunk;
            float m1 = m1v[j], m2 = m2v[j];
            int ci = civ[j];
            float smax = sigf(m1);
            float s = __fmul_rn(sigf(obv[j]), smax);
            unsigned int idx = L0END + a * 676 + cell0 + j;
            unsigned long long kv = 0ULL;
            if (s >= 0.5f)
                kv = ((unsigned long long)__float_as_uint(s) << 32) | (unsigned int)(~idx);
            keys[(size_t)img * NTOT + idx] = kv;
            if (s >= 0.5f) {
                int cid = ci;
                if (m2 >= m1 - NEARW || m1 > 8.0f)
                    cid = argmax_fallback(p0, 676, j, m1, smax);
                cls8[(size_t)img * CSTR + 512 + a * 676 + cell0 + j] = (unsigned char)cid;
            }
        }
    } else {
        // ---- level 2, float4 groups, 4-lane channel split ----
        int tt = t - 131072;
        int img = tt >> 13;
        int u = tt & 8191;
        int r = ((u >> 6) << 4) + (lane & 15);
        if (r < 2028) {
            int a = r / 676, grp = r - a * 676;
            int cell0 = grp * 4;
            const float* p0 = f2 + (size_t)img * 689520 + (size_t)(a * 85) * 2704 + cell0;
            float4 v4 = *(const float4*)(p0 + (5 + cbase) * 2704);
            float m1v[4] = {v4.x, v4.y, v4.z, v4.w};
            float m2v[4] = {-1e30f, -1e30f, -1e30f, -1e30f};
            int civ[4] = {cbase, cbase, cbase, cbase};
            #pragma unroll
            for (int c = 1; c < 20; ++c) {
                float4 w4 = *(const float4*)(p0 + (5 + cbase + c) * 2704);
                float vv[4] = {w4.x, w4.y, w4.z, w4.w};
                #pragma unroll
                for (int j = 0; j < 4; ++j) {
                    if (vv[j] > m1v[j]) { m2v[j] = m1v[j]; m1v[j] = vv[j]; civ[j] = cbase + c; }
                    else m2v[j] = fmaxf(m2v[j], vv[j]);
                }
            }
            #pragma unroll
            for (int j = 0; j < 4; ++j) {
                comb_step(m1v[j], m2v[j], civ[j], 16, low1);
                comb_step(m1v[j], m2v[j], civ[j], 32, low2);
            }
            float4 o4 = *(const float4*)(p0 + 4 * 2704);
            float obv[4] = {o4.x, o4.y, o4.z, o4.w};
            int j = chunk;
            float m1 = m1v[j], m2 = m2v[j];
            int ci = civ[j];
            float smax = sigf(m1);
            float s = __fmul_rn(sigf(obv[j]), smax);
            unsigned int idx = L1END + a * 2704 + cell0 + j;
            unsigned long long kv = 0ULL;
            if (s >= 0.5f)
                kv = ((unsigned long long)__float_as_uint(s) << 32) | (unsigned int)(~idx);
            keys[(size_t)img * NTOT + idx] = kv;
            if (s >= 0.5f) {
                int cid = ci;
                if (m2 >= m1 - NEARW || m1 > 8.0f)
                    cid = argmax_fallback(p0, 2704, j, m1, smax);
                cls8[(size_t)img * CSTR + 2540 + a * 2704 + cell0 + j] = (unsigned char)cid;
            }
        }
    }
}

// ---------------- kernel 2: top-300 — LDS-staged histogram select + exact rank ----------------
__global__ __launch_bounds__(1024) void topk_kernel(const unsigned long long* __restrict__ keys,
                                                    unsigned int* __restrict__ top_idx) {
    __shared__ unsigned long long s[NTOT];      // 85,176 B — staged keys
    __shared__ unsigned int hist[1024];
    __shared__ unsigned long long sel[SELCAP];  // 16 KiB
    __shared__ unsigned int wsum[16], wsuf[16];
    __shared__ unsigned int cnt;
    __shared__ int Tbin;

    int img = blockIdx.x;
    int tid = threadIdx.x;
    int wv = tid >> 6, ln = tid & 63;
    const unsigned long long* k = keys + (size_t)img * NTOT;

    hist[tid] = 0;
    if (tid == 0) { cnt = 0; Tbin = 0; }
    for (int i = tid; i < TOPK; i += 1024) top_idx[img * TOPK + i] = 0xFFFFFFFFu;
    __syncthreads();

    // stage + histogram in one global pass
    for (int i = tid; i < NTOT; i += 1024) {
        unsigned long long kv = k[i];
        s[i] = kv;
        unsigned int sb = (unsigned int)(kv >> 32);
        int bin = (int)(sb - 0x3F000000u) >> 13;   // negative for zero keys
        if (bin >= 0) {
            if (bin > 1023) bin = 1023;
            atomicAdd(&hist[bin], 1u);
        }
    }
    __syncthreads();

    // wave-level suffix scan of hist (scan[b] = sum_{b'>=b} hist[b'])
    unsigned int ssum = hist[tid];
    #pragma unroll
    for (int off = 1; off < 64; off <<= 1) {
        unsigned int o = __shfl_down(ssum, off, 64);
        if (ln + off < 64) ssum += o;
    }
    if (ln == 0) wsum[wv] = ssum;
    __syncthreads();
    if (wv == 0) {
        unsigned int tws = (ln < 16) ? wsum[ln] : 0u;
        #pragma unroll
        for (int off = 1; off < 16; off <<= 1) {
            unsigned int o = __shfl_down(tws, off, 64);
            if (ln + off < 16) tws += o;
        }
        if (ln < 16) wsuf[ln] = tws;   // wsuf[w] = sum over waves >= w
    }
    __syncthreads();
    {
        unsigned int higher = (wv < 15) ? wsuf[wv + 1] : 0u;
        unsigned int scanval = ssum + higher;                  // suffix sum from this bin
        unsigned int down1 = __shfl_down(scanval, 1, 64);
        unsigned int nextval = (ln < 63) ? down1 : higher;     // scan of bin+1 (tid=1023 -> 0)
        if (scanval >= TOPK && nextval < TOPK) Tbin = tid;     // unique transition
    }
    __syncthreads();
    int T = Tbin;

    // select from LDS: bin >= T
    for (int i = tid; i < NTOT; i += 1024) {
        unsigned long long kv = s[i];
        unsigned int sb = (unsigned int)(kv >> 32);
        int bin = (int)(sb - 0x3F000000u) >> 13;
        if (bin > 1023) bin = 1023;
        if (bin >= T) {
            unsigned int pos = atomicAdd(&cnt, 1u);
            if (pos < SELCAP) sel[pos] = kv;
        }
    }
    __syncthreads();
    int m = (int)cnt; if (m > SELCAP) m = SELCAP;

    // exact rank by pairwise comparison (keys unique), scatter rank < 300
    for (int i = tid; i < m; i += 1024) {
        unsigned long long ki = sel[i];
        int rank = 0;
        for (int j = 0; j < m; ++j) rank += (sel[j] > ki);
        if (rank < TOPK) top_idx[img * TOPK + rank] = ~((unsigned int)ki);
    }
}

// ---------------- kernel 3: slim decode + NMS (ballot bit-matrix + lane scan) ----------------
__global__ __launch_bounds__(1024) void nms_kernel(const float* __restrict__ f0,
                                                   const float* __restrict__ f1,
                                                   const float* __restrict__ f2,
                                                   const unsigned long long* __restrict__ keys,
                                                   const unsigned char* __restrict__ cls8,
                                                   const unsigned int* __restrict__ top_idx,
                                                   float* __restrict__ out) {
    __shared__ float bx0[TOPK], bx1[TOPK], bx2[TOPK], bx3[TOPK];
    __shared__ float bb0[TOPK], bb1[TOPK], bb2[TOPK], bb3[TOPK];
    __shared__ float area[TOPK], sc[TOPK], clsf[TOPK];
    __shared__ unsigned long long sup[TOPK][5];
    __shared__ unsigned long long keepm[5];

    int img = blockIdx.x;
    int tid = threadIdx.x;
    int wv = tid >> 6, ln = tid & 63;

    if (tid < TOPK) {
        unsigned int idx = top_idx[img * TOPK + tid];
        if (idx == 0xFFFFFFFFu) {
            bx0[tid] = 0.f; bx1[tid] = 0.f; bx2[tid] = 0.f; bx3[tid] = 0.f;
            bb0[tid] = 0.f; bb1[tid] = 0.f; bb2[tid] = 0.f; bb3[tid] = 0.f;
            area[tid] = 0.f; sc[tid] = 0.f; clsf[tid] = 0.f;
        } else {
            int level, hw, W, hrow, wcol, a;
            const float* p = locate(f0, f1, f2, img, (int)idx, level, hw, W, hrow, wcol, a);
            float tx = p[0];
            float ty = p[hw];
            float tw = p[2 * hw];
            float th = p[3 * hw];
            float score = __uint_as_float((unsigned int)(keys[(size_t)img * NTOT + idx] >> 32));
            int co = (idx < L0END) ? (int)idx
                     : (idx < L1END ? 512 + (int)idx - L0END : 2540 + (int)idx - L1END);
            int cid = cls8[(size_t)img * CSTR + co];

            float x = __fdiv_rn(__fadd_rn(sigf(tx), (float)wcol), (float)W);
            float y = __fdiv_rn(__fadd_rn(sigf(ty), (float)hrow), (float)W);   // H == W per level
            float wd = __fdiv_rn(__fmul_rn(expcr(tw), ANCWf[level][a]), 416.0f);
            float ht = __fdiv_rn(__fmul_rn(expcr(th), ANCHf[level][a]), 416.0f);

            float hx = __fmul_rn(wd, 0.5f);
            float hy = __fmul_rn(ht, 0.5f);
            float x1 = __fmul_rn(__fsub_rn(x, hx), 416.0f);
            float y1 = __fmul_rn(__fsub_rn(y, hy), 416.0f);
            float x2 = __fmul_rn(__fadd_rn(x, hx), 416.0f);
            float y2 = __fmul_rn(__fadd_rn(y, hy), 416.0f);
            float cf = (float)cid;
            float off = __fmul_rn(cf, 832.0f);   // 2*INPUT

            bx0[tid] = x1; bx1[tid] = y1; bx2[tid] = x2; bx3[tid] = y2;
            float b0 = __fadd_rn(x1, off), b1 = __fadd_rn(y1, off);
            float b2 = __fadd_rn(x2, off), b3 = __fadd_rn(y2, off);
            bb0[tid] = b0; bb1[tid] = b1; bb2[tid] = b2; bb3[tid] = b3;
            area[tid] = __fmul_rn(__fsub_rn(b2, b0), __fsub_rn(b3, b1));
            sc[tid] = score;
            clsf[tid] = cf;
        }
    }
    __syncthreads();

    // suppression bit-matrix, wave-parallel; lane's j-box kept in registers per w.
    #pragma unroll
    for (int w = 0; w < 5; ++w) {
        int j = (w << 6) + ln;
        bool jv = (j < TOPK);
        float j0 = jv ? bb0[j] : 0.0f;
        float j1 = jv ? bb1[j] : 0.0f;
        float j2 = jv ? bb2[j] : 0.0f;
        float j3 = jv ? bb3[j] : 0.0f;
        float ja = jv ? area[j] : 0.0f;
        for (int r = wv; r < TOPK; r += 16) {
            float a0 = bb0[r], a1 = bb1[r], a2 = bb2[r], a3 = bb3[r], aa = area[r];
            bool bit = false;
            if (jv && j > r) {
                float ltx = fmaxf(a0, j0);
                float lty = fmaxf(a1, j1);
                float rbx = fminf(a2, j2);
                float rby = fminf(a3, j3);
                float wx = fmaxf(__fsub_rn(rbx, ltx), 0.0f);
                float wy = fmaxf(__fsub_rn(rby, lty), 0.0f);
                float inter = __fmul_rn(wx, wy);
                float denom = __fadd_rn(__fsub_rn(__fadd_rn(aa, ja), inter), 1e-6f);
                float iou = __fdiv_rn(inter, denom);
                bit = (iou > 0.3f);
            }
            unsigned long long mm = __ballot(bit);
            if (ln == 0) sup[r][w] = mm;
        }
    }
    __syncthreads();

    // lane-parallel greedy scan by wave 0: lane w (w<5) owns keep-word kp.
    if (wv == 0) {
        unsigned long long kp = ~0ULL;
        for (int i = 0; i < TOPK; ++i) {
            unsigned long long kw = __shfl(kp, i >> 6, 64);
            bool keep_i = (kw >> (i & 63)) & 1ULL;
            if (keep_i && ln < 5) kp &= ~sup[i][ln];
        }
        if (ln < 5) keepm[ln] = kp;
    }
    __syncthreads();

    if (tid < TOPK) {
        bool kept = (keepm[tid >> 6] >> (tid & 63)) & 1ULL;
        float m = (kept && (sc[tid] > 0.0f)) ? 1.0f : 0.0f;
        float* o = out + ((size_t)img * TOPK + tid) * 6;
        o[0] = __fmul_rn(bx0[tid], m);
        o[1] = __fmul_rn(bx1[tid], m);
        o[2] = __fmul_rn(bx2[tid], m);
        o[3] = __fmul_rn(bx3[tid], m);
        o[4] = __fmul_rn(sc[tid], m);
        o[5] = __fmul_rn(clsf[tid], m);
    }
}

extern "C" void kernel_launch(void* const* d_in, const int* in_sizes, int n_in,
                              void* d_out, int out_size, void* d_ws, size_t ws_size,
                              hipStream_t stream) {
    const float* f0 = (const float*)d_in[0];
    const float* f1 = (const float*)d_in[1];
    const float* f2 = (const float*)d_in[2];
    float* out = (float*)d_out;

    int B = in_sizes[0] / 43095;   // 255*13*13 (== 32 for this problem)

    // workspace: [keys B*NTOT u64][cls8 B*CSTR u8][top_idx B*300 u32]
    unsigned long long* keys = (unsigned long long*)d_ws;
    size_t off1 = (size_t)B * NTOT * sizeof(unsigned long long);
    unsigned char* cls8 = (unsigned char*)d_ws + off1;
    size_t off2 = (off1 + (size_t)B * CSTR + 255) / 256 * 256;
    unsigned int* top_idx = (unsigned int*)((char*)d_ws + off2);

    // threads: 65536 (L0) + 65536 (L1) + 262144 (L2) = 393216
    score_kernel<<<393216 / 256, 256, 0, stream>>>(f0, f1, f2, keys, cls8);
    topk_kernel<<<B, 1024, 0, stream>>>(keys, top_idx);
    nms_kernel<<<B, 1024, 0, stream>>>(f0, f1, f2, keys, cls8, top_idx, out);
}

// Round 17
// 104.224 us; speedup vs baseline: 1.4435x; 1.0889x over previous
//
#include <hip/hip_runtime.h>
#include <math.h>

// ---------------- problem constants ----------------
#define NUM_CLASSES 80
#define TOPK 300
#define NTOT 10647             // 3*(169+676+2704)
#define L0END 507
#define L1END 2535
#define SELCAP 2048
#define CSTR 10656             // per-image cls stride: L0 [0,512) L1 [512,2540) L2 [2540,10652)
#define DELTA 0.25f            // near-max candidate window for exact sigmoid-argmax
#define NEARW 1e-3f            // m1-m2 gap below which sigf collision is possible

// level 0: 13x13 (mask 6,7,8), level 1: 26x26 (mask 3,4,5), level 2: 52x52 (mask 0,1,2)
__constant__ float ANCWf[3][3] = {{116.f,156.f,373.f},{30.f,62.f,59.f},{10.f,16.f,33.f}};
__constant__ float ANCHf[3][3] = {{90.f,198.f,326.f},{61.f,45.f,119.f},{13.f,30.f,23.f}};

// correctly-rounded f32 exp (f64 exp, rounded once) — matches numpy f32 exp
__device__ __forceinline__ float expcr(float x) { return (float)exp((double)x); }
// numpy-style f32 sigmoid: op-by-op 1/(1+exp(-x)), each op f32 correctly rounded
__device__ __forceinline__ float sigf(float x) {
    float e = expcr(-x);
    return __fdiv_rn(1.0f, __fadd_rn(1.0f, e));
}

// locate anchor idx -> level geometry + channel-0 pointer (stride hw between channels)
__device__ __forceinline__ const float* locate(const float* f0, const float* f1, const float* f2,
                                               int img, int idx,
                                               int& level, int& hw, int& W, int& hrow, int& wcol, int& a) {
    int local, cell;
    const float* base;
    if (idx < L0END) {
        level = 0; local = idx; hw = 169; W = 13;
        base = f0 + (size_t)img * 43095;        // 255*169
    } else if (idx < L1END) {
        level = 1; local = idx - L0END; hw = 676; W = 26;
        base = f1 + (size_t)img * 172380;       // 255*676
    } else {
        level = 2; local = idx - L1END; hw = 2704; W = 52;
        base = f2 + (size_t)img * 689520;       // 255*2704
    }
    a = local / hw; cell = local - a * hw;
    hrow = cell / W; wcol = cell - hrow * W;
    return base + (size_t)(a * 85) * hw + cell;
}

// exact first-wins sigmoid-argmax fallback (rare): first c with sigf(l_c)==smax
template <int HW>
__device__ __forceinline__ int argmax_fallback(const float* p, float m1, float smax) {
    for (int c = 0; c < NUM_CLASSES; ++c) {
        float v = p[(5 + c) * HW];
        if (v >= m1 - DELTA && sigf(v) == smax) return c;
    }
    return 0;
}

// one-anchor score/class: obj-gated early exit (sigf(obj)<0.5 => score<0.5 exactly,
// since RN-mul by sigf(mx)<=1.0 cannot exceed sigf(obj)); else full first-wins
// strict-> logit scan tracking (m1,m2,ci); NEARW/8.0 guard -> exact fallback.
template <int HW>
__device__ __forceinline__ void score_anchor(const float* p, unsigned int idx,
                                             unsigned long long* kslot,
                                             unsigned char* cslot) {
    float e = expcr(-p[4 * HW]);
    float sobj = __fdiv_rn(1.0f, __fadd_rn(1.0f, e));
    if (sobj < 0.5f) { *kslot = 0ULL; return; }
    float m1 = p[5 * HW], m2 = -1e30f;
    int ci = 0;
    #pragma unroll 16
    for (int c = 1; c < NUM_CLASSES; ++c) {
        float v = p[(5 + c) * HW];
        if (v > m1) { m2 = m1; m1 = v; ci = c; }
        else m2 = fmaxf(m2, v);
    }
    float smax = sigf(m1);
    float s = __fmul_rn(sobj, smax);
    unsigned long long kv = 0ULL;
    if (s >= 0.5f)
        kv = ((unsigned long long)__float_as_uint(s) << 32) | (unsigned int)(~idx);
    *kslot = kv;
    if (s >= 0.5f) {
        int cid = ci;
        if (m2 >= m1 - NEARW || m1 > 8.0f)
            cid = argmax_fallback<HW>(p, m1, smax);
        *cslot = (unsigned char)cid;
    }
}

// ---------------- kernel 1: one thread per anchor, scalar coalesced loads ----------------
// Thread ranges (wave-aligned per image & level):
//   L0 [0, 16384):        img=t>>9,  r=t&511,  valid r<507  (3*169)
//   L1 [16384, 81920):    img=tt>>11, r=tt&2047, valid r<2028 (3*676)
//   L2 [81920, 344064):   img=tt>>13, r=tt&8191, valid r<8112 (3*2704)
__global__ void score_kernel(const float* __restrict__ f0, const float* __restrict__ f1,
                             const float* __restrict__ f2,
                             unsigned long long* __restrict__ keys,
                             unsigned char* __restrict__ cls8) {
    int t = blockIdx.x * blockDim.x + threadIdx.x;

    if (t < 16384) {
        int img = t >> 9;
        int r = t & 511;
        if (r < 507) {
            int a = r / 169, cell = r - a * 169;
            const float* p = f0 + (size_t)img * 43095 + (size_t)(a * 85) * 169 + cell;
            score_anchor<169>(p, (unsigned int)r,
                              keys + (size_t)img * NTOT + r,
                              cls8 + (size_t)img * CSTR + r);
        }
    } else if (t < 81920) {
        int tt = t - 16384;
        int img = tt >> 11;
        int r = tt & 2047;
        if (r < 2028) {
            int a = r / 676, cell = r - a * 676;
            const float* p = f1 + (size_t)img * 172380 + (size_t)(a * 85) * 676 + cell;
            score_anchor<676>(p, (unsigned int)(L0END + r),
                              keys + (size_t)img * NTOT + L0END + r,
                              cls8 + (size_t)img * CSTR + 512 + r);
        }
    } else {
        int tt = t - 81920;
        int img = tt >> 13;
        int r = tt & 8191;
        if (r < 8112) {
            int a = r / 2704, cell = r - a * 2704;
            const float* p = f2 + (size_t)img * 689520 + (size_t)(a * 85) * 2704 + cell;
            score_anchor<2704>(p, (unsigned int)(L1END + r),
                               keys + (size_t)img * NTOT + L1END + r,
                               cls8 + (size_t)img * CSTR + 2540 + r);
        }
    }
}

// ---------------- kernel 2: top-300 — LDS-staged histogram select + exact rank ----------------
__global__ __launch_bounds__(1024) void topk_kernel(const unsigned long long* __restrict__ keys,
                                                    unsigned int* __restrict__ top_idx) {
    __shared__ unsigned long long s[NTOT];      // 85,176 B — staged keys
    __shared__ unsigned int hist[1024];
    __shared__ unsigned long long sel[SELCAP];  // 16 KiB
    __shared__ unsigned int wsum[16], wsuf[16];
    __shared__ unsigned int cnt;
    __shared__ int Tbin;

    int img = blockIdx.x;
    int tid = threadIdx.x;
    int wv = tid >> 6, ln = tid & 63;
    const unsigned long long* k = keys + (size_t)img * NTOT;

    hist[tid] = 0;
    if (tid == 0) { cnt = 0; Tbin = 0; }
    for (int i = tid; i < TOPK; i += 1024) top_idx[img * TOPK + i] = 0xFFFFFFFFu;
    __syncthreads();

    // stage + histogram in one global pass
    for (int i = tid; i < NTOT; i += 1024) {
        unsigned long long kv = k[i];
        s[i] = kv;
        unsigned int sb = (unsigned int)(kv >> 32);
        int bin = (int)(sb - 0x3F000000u) >> 13;   // negative for zero keys
        if (bin >= 0) {
            if (bin > 1023) bin = 1023;
            atomicAdd(&hist[bin], 1u);
        }
    }
    __syncthreads();

    // wave-level suffix scan of hist (scan[b] = sum_{b'>=b} hist[b'])
    unsigned int ssum = hist[tid];
    #pragma unroll
    for (int off = 1; off < 64; off <<= 1) {
        unsigned int o = __shfl_down(ssum, off, 64);
        if (ln + off < 64) ssum += o;
    }
    if (ln == 0) wsum[wv] = ssum;
    __syncthreads();
    if (wv == 0) {
        unsigned int tws = (ln < 16) ? wsum[ln] : 0u;
        #pragma unroll
        for (int off = 1; off < 16; off <<= 1) {
            unsigned int o = __shfl_down(tws, off, 64);
            if (ln + off < 16) tws += o;
        }
        if (ln < 16) wsuf[ln] = tws;   // wsuf[w] = sum over waves >= w
    }
    __syncthreads();
    {
        unsigned int higher = (wv < 15) ? wsuf[wv + 1] : 0u;
        unsigned int scanval = ssum + higher;                  // suffix sum from this bin
        unsigned int down1 = __shfl_down(scanval, 1, 64);
        unsigned int nextval = (ln < 63) ? down1 : higher;     // scan of bin+1 (tid=1023 -> 0)
        if (scanval >= TOPK && nextval < TOPK) Tbin = tid;     // unique transition
    }
    __syncthreads();
    int T = Tbin;

    // select from LDS: bin >= T
    for (int i = tid; i < NTOT; i += 1024) {
        unsigned long long kv = s[i];
        unsigned int sb = (unsigned int)(kv >> 32);
        int bin = (int)(sb - 0x3F000000u) >> 13;
        if (bin > 1023) bin = 1023;
        if (bin >= T) {
            unsigned int pos = atomicAdd(&cnt, 1u);
            if (pos < SELCAP) sel[pos] = kv;
        }
    }
    __syncthreads();
    int m = (int)cnt; if (m > SELCAP) m = SELCAP;

    // exact rank by pairwise comparison (keys unique), scatter rank < 300
    for (int i = tid; i < m; i += 1024) {
        unsigned long long ki = sel[i];
        int rank = 0;
        for (int j = 0; j < m; ++j) rank += (sel[j] > ki);
        if (rank < TOPK) top_idx[img * TOPK + rank] = ~((unsigned int)ki);
    }
}

// ---------------- kernel 3: slim decode + NMS (ballot bit-matrix + lane scan) ----------------
__global__ __launch_bounds__(1024) void nms_kernel(const float* __restrict__ f0,
                                                   const float* __restrict__ f1,
                                                   const float* __restrict__ f2,
                                                   const unsigned long long* __restrict__ keys,
                                                   const unsigned char* __restrict__ cls8,
                                                   const unsigned int* __restrict__ top_idx,
                                                   float* __restrict__ out) {
    __shared__ float bx0[TOPK], bx1[TOPK], bx2[TOPK], bx3[TOPK];
    __shared__ float bb0[TOPK], bb1[TOPK], bb2[TOPK], bb3[TOPK];
    __shared__ float area[TOPK], sc[TOPK], clsf[TOPK];
    __shared__ unsigned long long sup[TOPK][5];
    __shared__ unsigned long long keepm[5];

    int img = blockIdx.x;
    int tid = threadIdx.x;
    int wv = tid >> 6, ln = tid & 63;

    if (tid < TOPK) {
        unsigned int idx = top_idx[img * TOPK + tid];
        if (idx == 0xFFFFFFFFu) {
            bx0[tid] = 0.f; bx1[tid] = 0.f; bx2[tid] = 0.f; bx3[tid] = 0.f;
            bb0[tid] = 0.f; bb1[tid] = 0.f; bb2[tid] = 0.f; bb3[tid] = 0.f;
            area[tid] = 0.f; sc[tid] = 0.f; clsf[tid] = 0.f;
        } else {
            int level, hw, W, hrow, wcol, a;
            const float* p = locate(f0, f1, f2, img, (int)idx, level, hw, W, hrow, wcol, a);
            float tx = p[0];
            float ty = p[hw];
            float tw = p[2 * hw];
            float th = p[3 * hw];
            float score = __uint_as_float((unsigned int)(keys[(size_t)img * NTOT + idx] >> 32));
            int co = (idx < L0END) ? (int)idx
                     : (idx < L1END ? 512 + (int)idx - L0END : 2540 + (int)idx - L1END);
            int cid = cls8[(size_t)img * CSTR + co];

            float x = __fdiv_rn(__fadd_rn(sigf(tx), (float)wcol), (float)W);
            float y = __fdiv_rn(__fadd_rn(sigf(ty), (float)hrow), (float)W);   // H == W per level
            float wd = __fdiv_rn(__fmul_rn(expcr(tw), ANCWf[level][a]), 416.0f);
            float ht = __fdiv_rn(__fmul_rn(expcr(th), ANCHf[level][a]), 416.0f);

            float hx = __fmul_rn(wd, 0.5f);
            float hy = __fmul_rn(ht, 0.5f);
            float x1 = __fmul_rn(__fsub_rn(x, hx), 416.0f);
            float y1 = __fmul_rn(__fsub_rn(y, hy), 416.0f);
            float x2 = __fmul_rn(__fadd_rn(x, hx), 416.0f);
            float y2 = __fmul_rn(__fadd_rn(y, hy), 416.0f);
            float cf = (float)cid;
            float off = __fmul_rn(cf, 832.0f);   // 2*INPUT

            bx0[tid] = x1; bx1[tid] = y1; bx2[tid] = x2; bx3[tid] = y2;
            float b0 = __fadd_rn(x1, off), b1 = __fadd_rn(y1, off);
            float b2 = __fadd_rn(x2, off), b3 = __fadd_rn(y2, off);
            bb0[tid] = b0; bb1[tid] = b1; bb2[tid] = b2; bb3[tid] = b3;
            area[tid] = __fmul_rn(__fsub_rn(b2, b0), __fsub_rn(b3, b1));
            sc[tid] = score;
            clsf[tid] = cf;
        }
    }
    __syncthreads();

    // suppression bit-matrix, wave-parallel; lane's j-box kept in registers per w.
    #pragma unroll
    for (int w = 0; w < 5; ++w) {
        int j = (w << 6) + ln;
        bool jv = (j < TOPK);
        float j0 = jv ? bb0[j] : 0.0f;
        float j1 = jv ? bb1[j] : 0.0f;
        float j2 = jv ? bb2[j] : 0.0f;
        float j3 = jv ? bb3[j] : 0.0f;
        float ja = jv ? area[j] : 0.0f;
        for (int r = wv; r < TOPK; r += 16) {
            float a0 = bb0[r], a1 = bb1[r], a2 = bb2[r], a3 = bb3[r], aa = area[r];
            bool bit = false;
            if (jv && j > r) {
                float ltx = fmaxf(a0, j0);
                float lty = fmaxf(a1, j1);
                float rbx = fminf(a2, j2);
                float rby = fminf(a3, j3);
                float wx = fmaxf(__fsub_rn(rbx, ltx), 0.0f);
                float wy = fmaxf(__fsub_rn(rby, lty), 0.0f);
                float inter = __fmul_rn(wx, wy);
                float denom = __fadd_rn(__fsub_rn(__fadd_rn(aa, ja), inter), 1e-6f);
                float iou = __fdiv_rn(inter, denom);
                bit = (iou > 0.3f);
            }
            unsigned long long mm = __ballot(bit);
            if (ln == 0) sup[r][w] = mm;
        }
    }
    __syncthreads();

    // lane-parallel greedy scan by wave 0: lane w (w<5) owns keep-word kp.
    if (wv == 0) {
        unsigned long long kp = ~0ULL;
        for (int i = 0; i < TOPK; ++i) {
            unsigned long long kw = __shfl(kp, i >> 6, 64);
            bool keep_i = (kw >> (i & 63)) & 1ULL;
            if (keep_i && ln < 5) kp &= ~sup[i][ln];
        }
        if (ln < 5) keepm[ln] = kp;
    }
    __syncthreads();

    if (tid < TOPK) {
        bool kept = (keepm[tid >> 6] >> (tid & 63)) & 1ULL;
        float m = (kept && (sc[tid] > 0.0f)) ? 1.0f : 0.0f;
        float* o = out + ((size_t)img * TOPK + tid) * 6;
        o[0] = __fmul_rn(bx0[tid], m);
        o[1] = __fmul_rn(bx1[tid], m);
        o[2] = __fmul_rn(bx2[tid], m);
        o[3] = __fmul_rn(bx3[tid], m);
        o[4] = __fmul_rn(sc[tid], m);
        o[5] = __fmul_rn(clsf[tid], m);
    }
}

extern "C" void kernel_launch(void* const* d_in, const int* in_sizes, int n_in,
                              void* d_out, int out_size, void* d_ws, size_t ws_size,
                              hipStream_t stream) {
    const float* f0 = (const float*)d_in[0];
    const float* f1 = (const float*)d_in[1];
    const float* f2 = (const float*)d_in[2];
    float* out = (float*)d_out;

    int B = in_sizes[0] / 43095;   // 255*13*13 (== 32 for this problem)

    // workspace: [keys B*NTOT u64][cls8 B*CSTR u8][top_idx B*300 u32]
    unsigned long long* keys = (unsigned long long*)d_ws;
    size_t off1 = (size_t)B * NTOT * sizeof(unsigned long long);
    unsigned char* cls8 = (unsigned char*)d_ws + off1;
    size_t off2 = (off1 + (size_t)B * CSTR + 255) / 256 * 256;
    unsigned int* top_idx = (unsigned int*)((char*)d_ws + off2);

    // threads: 16384 (L0) + 65536 (L1) + 262144 (L2) = 344064
    score_kernel<<<344064 / 256, 256, 0, stream>>>(f0, f1, f2, keys, cls8);
    topk_kernel<<<B, 1024, 0, stream>>>(keys, top_idx);
    nms_kernel<<<B, 1024, 0, stream>>>(f0, f1, f2, keys, cls8, top_idx, out);
}